// Round 1
// baseline (343.148 us; speedup 1.0000x reference)
//
#include <hip/hip_runtime.h>
#include <math.h>

typedef short  short8  __attribute__((ext_vector_type(8)));
typedef short  short4v __attribute__((ext_vector_type(4)));
typedef float  f32x4   __attribute__((ext_vector_type(4)));

#define BATCH 32768
#define DIN   256
#define DOUT  512
#define BM    128
#define BN    128
#define BK    32

// round-to-nearest-even fp32 -> bf16 bits
__device__ __forceinline__ short f2bf(float v) {
    unsigned u = __float_as_uint(v);
    u += 0x7fffu + ((u >> 16) & 1u);
    return (short)(u >> 16);
}
__device__ __forceinline__ float bf2f(short s) {
    return __uint_as_float(((unsigned)(unsigned short)s) << 16);
}

// Stage a 128x32 fp32 tile from global into LDS as bf16 hi+lo (error split).
// Layout: row-major [128][32] halves, with XOR granule swizzle
// g' = g ^ ((row>>1)&3)  (granule = 8 halves) so the wave's ds_read_b128
// pattern is only 2-way bank-aliased (free on gfx950, m136).
__device__ __forceinline__ void stage_split(const float* __restrict__ g, int ld,
                                            int row0, int k0, int tid,
                                            short* sh, short* sl) {
#pragma unroll
    for (int i = 0; i < 4; i++) {
        int p  = tid + i * 256;      // float4 index within the 128x32 tile
        int r  = p >> 3;             // tile row
        int c4 = p & 7;              // float4 column (k = c4*4)
        const float4 v = *(const float4*)(g + (size_t)(row0 + r) * ld + k0 + c4 * 4);
        float vv[4] = {v.x, v.y, v.z, v.w};
        short h[4], l[4];
#pragma unroll
        for (int j = 0; j < 4; j++) {
            h[j] = f2bf(vv[j]);
            l[j] = f2bf(vv[j] - bf2f(h[j]));   // v - hi is exact in fp32
        }
        int gsw  = (c4 >> 1) ^ ((r >> 1) & 3);
        int addr = r * 32 + gsw * 8 + (c4 & 1) * 4;
        *(short4v*)(sh + addr) = (short4v){h[0], h[1], h[2], h[3]};
        *(short4v*)(sl + addr) = (short4v){l[0], l[1], l[2], l[3]};
    }
}

// Same but hi-only (for the recurrent GEMM: spikes are {0,1}, exact in bf16).
__device__ __forceinline__ void stage_plain(const float* __restrict__ g, int ld,
                                            int row0, int k0, int tid,
                                            short* sh) {
#pragma unroll
    for (int i = 0; i < 4; i++) {
        int p  = tid + i * 256;
        int r  = p >> 3;
        int c4 = p & 7;
        const float4 v = *(const float4*)(g + (size_t)(row0 + r) * ld + k0 + c4 * 4);
        short h[4] = {f2bf(v.x), f2bf(v.y), f2bf(v.z), f2bf(v.w)};
        int gsw  = (c4 >> 1) ^ ((r >> 1) & 3);
        int addr = r * 32 + gsw * 8 + (c4 & 1) * 4;
        *(short4v*)(sh + addr) = (short4v){h[0], h[1], h[2], h[3]};
    }
}

__global__ __launch_bounds__(256, 2) void spike_rnn_lif_kernel(
    const float* __restrict__ X,    // input_spike [B, 256]
    const float* __restrict__ MEM,  // [B, 512]
    const float* __restrict__ SPK,  // [B, 512]
    const float* __restrict__ Wd,   // [512, 256]
    const float* __restrict__ bd,   // [512]
    const float* __restrict__ Wr,   // [512, 512]
    const float* __restrict__ br,   // [512]
    const float* __restrict__ tau,  // [512]
    float* __restrict__ out)        // [2, B, 512]: mem_new then spike_new
{
    __shared__ short sAh[BM * BK];
    __shared__ short sAl[BM * BK];
    __shared__ short sBh[BN * BK];
    __shared__ short sBl[BN * BK];

    const int tid  = threadIdx.x;
    const int lane = tid & 63;
    const int w    = tid >> 6;        // wave id 0..3
    const int wm   = w & 1;           // wave tile: 64x64 within 128x128
    const int wn   = w >> 1;
    const int bn   = blockIdx.x;      // 0..3   (n-blocks adjacent -> A-tile L2 reuse)
    const int bm   = blockIdx.y;      // 0..255
    const int m0   = bm * BM;
    const int n0   = bn * BN;
    const int col  = lane & 15;
    const int quad = lane >> 4;

    f32x4 acc[4][4];
#pragma unroll
    for (int i = 0; i < 4; i++)
#pragma unroll
        for (int j = 0; j < 4; j++)
            acc[i][j] = (f32x4){0.f, 0.f, 0.f, 0.f};

    // ---- Phase 1: dense GEMM, K=256, bf16x2 split (hi*hi + hi*lo + lo*hi) ----
    for (int kb = 0; kb < DIN; kb += BK) {
        __syncthreads();
        stage_split(X,  DIN, m0, kb, tid, sAh, sAl);
        stage_split(Wd, DIN, n0, kb, tid, sBh, sBl);
        __syncthreads();

        short8 ah[4], al[4], bh[4], bl[4];
#pragma unroll
        for (int t = 0; t < 4; t++) {
            int ra = wm * 64 + t * 16 + col;
            int ia = ra * 32 + (quad ^ ((ra >> 1) & 3)) * 8;
            ah[t] = *(const short8*)(sAh + ia);
            al[t] = *(const short8*)(sAl + ia);
            int rb = wn * 64 + t * 16 + col;
            int ib = rb * 32 + (quad ^ ((rb >> 1) & 3)) * 8;
            bh[t] = *(const short8*)(sBh + ib);
            bl[t] = *(const short8*)(sBl + ib);
        }
#pragma unroll
        for (int i = 0; i < 4; i++)
#pragma unroll
            for (int j = 0; j < 4; j++) {
                acc[i][j] = __builtin_amdgcn_mfma_f32_16x16x32_bf16(ah[i], bh[j], acc[i][j], 0, 0, 0);
                acc[i][j] = __builtin_amdgcn_mfma_f32_16x16x32_bf16(ah[i], bl[j], acc[i][j], 0, 0, 0);
                acc[i][j] = __builtin_amdgcn_mfma_f32_16x16x32_bf16(al[i], bh[j], acc[i][j], 0, 0, 0);
            }
    }

    // ---- Phase 2: recurrent GEMM, K=512, plain bf16 (spikes exact in bf16) ----
    for (int kb = 0; kb < DOUT; kb += BK) {
        __syncthreads();
        stage_plain(SPK, DOUT, m0, kb, tid, sAh);
        stage_plain(Wr,  DOUT, n0, kb, tid, sBh);
        __syncthreads();

        short8 ah[4], bh[4];
#pragma unroll
        for (int t = 0; t < 4; t++) {
            int ra = wm * 64 + t * 16 + col;
            ah[t] = *(const short8*)(sAh + ra * 32 + (quad ^ ((ra >> 1) & 3)) * 8);
            int rb = wn * 64 + t * 16 + col;
            bh[t] = *(const short8*)(sBh + rb * 32 + (quad ^ ((rb >> 1) & 3)) * 8);
        }
#pragma unroll
        for (int i = 0; i < 4; i++)
#pragma unroll
            for (int j = 0; j < 4; j++)
                acc[i][j] = __builtin_amdgcn_mfma_f32_16x16x32_bf16(ah[i], bh[j], acc[i][j], 0, 0, 0);
    }

    // ---- Epilogue: LIF dynamics, fused ----
    // C/D layout (m89/m91-verified): col = lane&15, row = (lane>>4)*4 + reg
#pragma unroll
    for (int j = 0; j < 4; j++) {
        int n = n0 + wn * 64 + j * 16 + col;
        float alpha = expf(-1.0f / tau[n]);
        float bsum  = bd[n] + br[n];
#pragma unroll
        for (int i = 0; i < 4; i++) {
            int mbase = m0 + wm * 64 + i * 16 + quad * 4;
#pragma unroll
            for (int rr = 0; rr < 4; rr++) {
                size_t idx = (size_t)(mbase + rr) * DOUT + n;
                float d       = acc[i][j][rr] + bsum;
                float mem_new = MEM[idx] * alpha + (1.0f - alpha) * d - 0.5f * SPK[idx];
                out[idx] = mem_new;
                out[(size_t)BATCH * DOUT + idx] = (mem_new - 0.5f > 0.0f) ? 1.0f : 0.0f;
            }
        }
    }
}

extern "C" void kernel_launch(void* const* d_in, const int* in_sizes, int n_in,
                              void* d_out, int out_size, void* d_ws, size_t ws_size,
                              hipStream_t stream) {
    const float* X   = (const float*)d_in[0];
    const float* MEM = (const float*)d_in[1];
    const float* SPK = (const float*)d_in[2];
    const float* Wd  = (const float*)d_in[3];
    const float* bd  = (const float*)d_in[4];
    const float* Wr  = (const float*)d_in[5];
    const float* br  = (const float*)d_in[6];
    const float* tau = (const float*)d_in[7];

    dim3 grid(DOUT / BN, BATCH / BM);   // (4, 256): n-blocks adjacent for L2 reuse
    spike_rnn_lif_kernel<<<grid, 256, 0, stream>>>(X, MEM, SPK, Wd, bd, Wr, br, tau,
                                                   (float*)d_out);
}